// Round 1
// baseline (151.440 us; speedup 1.0000x reference)
//
#include <hip/hip_runtime.h>

#define CC 256
#define HH 200
#define WW 304
#define PHW 49   // 7*7

struct Interp { int lo, hi; float w0, w1; };

__device__ __forceinline__ Interp axis_interp(float coord, int size) {
  float valid = (coord >= -1.0f && coord <= (float)size) ? 1.0f : 0.0f;
  float c = fminf(fmaxf(coord, 0.0f), (float)(size - 1));
  float fl = floorf(c);
  int lo = (int)fl;
  int hi = min(lo + 1, size - 1);
  float fr = c - fl;
  Interp r;
  r.lo = lo; r.hi = hi;
  r.w0 = (1.0f - fr) * valid;
  r.w1 = fr * valid;
  return r;
}

// NCHW -> NHWC transpose: dst[((b*H+y)*W+x)*C + c] = src[((b*C+c)*H+y)*W + x]
__global__ __launch_bounds__(256) void k_transpose(const float* __restrict__ src,
                                                   float* __restrict__ dst) {
  __shared__ float tile[32][33];
  int plane = blockIdx.z;              // b*HH + y
  int x0 = blockIdx.x * 32;
  int c0 = blockIdx.y * 32;
  int b = plane / HH;
  int y = plane - b * HH;
  const float* sp = src + (size_t)b * CC * HH * WW + (size_t)y * WW;
  float* dp = dst + (size_t)plane * WW * CC;
  int tx = threadIdx.x & 31;
  int ty = threadIdx.x >> 5;           // 0..7
#pragma unroll
  for (int q = 0; q < 4; ++q) {
    int c = c0 + ty + q * 8;
    int x = x0 + tx;
    if (x < WW) tile[ty + q * 8][tx] = sp[(size_t)c * HH * WW + x];
  }
  __syncthreads();
#pragma unroll
  for (int q = 0; q < 4; ++q) {
    int x = x0 + ty + q * 8;
    int c = c0 + tx;
    if (x < WW) dp[(size_t)x * CC + c] = tile[tx][ty + q * 8];
  }
}

// One block (256 thr = 4 waves) per ROI. Wave handles bins p = wave, wave+4, ...
// Lane holds channels [4*lane, 4*lane+4). NHWC gathers are coalesced float4.
__global__ __launch_bounds__(256) void k_roialign_nhwc(const float* __restrict__ fe,
                                                       const float* __restrict__ rois,
                                                       float* __restrict__ out) {
  __shared__ float lds[PHW * 257];     // [p][c] padded: addr = p*257 + c
  int k = blockIdx.x;
  const float* r = rois + (size_t)k * 5;
  int b = (int)r[0];
  float x1 = r[1] * 0.25f, y1 = r[2] * 0.25f;
  float x2 = r[3] * 0.25f, y2 = r[4] * 0.25f;
  float bin_w = fmaxf(x2 - x1, 1.0f) * (1.0f / 7.0f);
  float bin_h = fmaxf(y2 - y1, 1.0f) * (1.0f / 7.0f);

  int wave = threadIdx.x >> 6;
  int lane = threadIdx.x & 63;
  const float* base = fe + (size_t)b * HH * WW * CC + (size_t)lane * 4;

  for (int p = wave; p < PHW; p += 4) {
    int ph = p / 7;
    int pw = p - ph * 7;
    float4 acc = make_float4(0.f, 0.f, 0.f, 0.f);
#pragma unroll
    for (int sy = 0; sy < 2; ++sy) {
      float yy = y1 + ((float)(2 * ph + sy) + 0.5f) * 0.5f * bin_h;
      Interp iy = axis_interp(yy, HH);
#pragma unroll
      for (int sx = 0; sx < 2; ++sx) {
        float xx = x1 + ((float)(2 * pw + sx) + 0.5f) * 0.5f * bin_w;
        Interp ix = axis_interp(xx, WW);
        const float4 v00 = *(const float4*)(base + ((size_t)iy.lo * WW + ix.lo) * CC);
        const float4 v01 = *(const float4*)(base + ((size_t)iy.lo * WW + ix.hi) * CC);
        const float4 v10 = *(const float4*)(base + ((size_t)iy.hi * WW + ix.lo) * CC);
        const float4 v11 = *(const float4*)(base + ((size_t)iy.hi * WW + ix.hi) * CC);
        float w00 = iy.w0 * ix.w0, w01 = iy.w0 * ix.w1;
        float w10 = iy.w1 * ix.w0, w11 = iy.w1 * ix.w1;
        acc.x += w00 * v00.x + w01 * v01.x + w10 * v10.x + w11 * v11.x;
        acc.y += w00 * v00.y + w01 * v01.y + w10 * v10.y + w11 * v11.y;
        acc.z += w00 * v00.z + w01 * v01.z + w10 * v10.z + w11 * v11.z;
        acc.w += w00 * v00.w + w01 * v01.w + w10 * v10.w + w11 * v11.w;
      }
    }
    int o = p * 257 + lane * 4;
    lds[o + 0] = acc.x * 0.25f;
    lds[o + 1] = acc.y * 0.25f;
    lds[o + 2] = acc.z * 0.25f;
    lds[o + 3] = acc.w * 0.25f;
  }
  __syncthreads();

  // Coalesced write of this ROI's contiguous (C,7,7) block.
  float* outk = out + (size_t)k * CC * PHW;
  for (int i = threadIdx.x; i < CC * PHW; i += 256) {
    int c = i / PHW;
    int p = i - c * PHW;
    outk[i] = lds[p * 257 + c];
  }
}

// Fallback if workspace can't hold the NHWC copy: one thread per output element,
// scalar NCHW gathers (coalesced-ish spatial locality within a wave).
__global__ __launch_bounds__(256) void k_roialign_direct(const float* __restrict__ fe,
                                                         const float* __restrict__ rois,
                                                         float* __restrict__ out,
                                                         int total) {
  int idx = blockIdx.x * 256 + threadIdx.x;
  if (idx >= total) return;
  int pw = idx % 7;
  int t = idx / 7;
  int ph = t % 7; t /= 7;
  int c = t % CC;
  int k = t / CC;
  const float* r = rois + (size_t)k * 5;
  int b = (int)r[0];
  float x1 = r[1] * 0.25f, y1 = r[2] * 0.25f;
  float x2 = r[3] * 0.25f, y2 = r[4] * 0.25f;
  float bin_w = fmaxf(x2 - x1, 1.0f) * (1.0f / 7.0f);
  float bin_h = fmaxf(y2 - y1, 1.0f) * (1.0f / 7.0f);
  const float* base = fe + ((size_t)b * CC + c) * HH * WW;
  float acc = 0.f;
#pragma unroll
  for (int sy = 0; sy < 2; ++sy) {
    float yy = y1 + ((float)(2 * ph + sy) + 0.5f) * 0.5f * bin_h;
    Interp iy = axis_interp(yy, HH);
#pragma unroll
    for (int sx = 0; sx < 2; ++sx) {
      float xx = x1 + ((float)(2 * pw + sx) + 0.5f) * 0.5f * bin_w;
      Interp ix = axis_interp(xx, WW);
      float v00 = base[(size_t)iy.lo * WW + ix.lo];
      float v01 = base[(size_t)iy.lo * WW + ix.hi];
      float v10 = base[(size_t)iy.hi * WW + ix.lo];
      float v11 = base[(size_t)iy.hi * WW + ix.hi];
      acc += iy.w0 * ix.w0 * v00 + iy.w0 * ix.w1 * v01 +
             iy.w1 * ix.w0 * v10 + iy.w1 * ix.w1 * v11;
    }
  }
  out[idx] = acc * 0.25f;
}

extern "C" void kernel_launch(void* const* d_in, const int* in_sizes, int n_in,
                              void* d_out, int out_size, void* d_ws, size_t ws_size,
                              hipStream_t stream) {
  const float* features = (const float*)d_in[0];
  const float* rois = (const float*)d_in[1];
  float* out = (float*)d_out;
  int B = in_sizes[0] / (CC * HH * WW);
  int K = in_sizes[1] / 5;
  size_t need = (size_t)B * HH * WW * CC * sizeof(float);
  if (ws_size >= need) {
    dim3 tg((WW + 31) / 32, CC / 32, B * HH);
    k_transpose<<<tg, 256, 0, stream>>>(features, (float*)d_ws);
    k_roialign_nhwc<<<K, 256, 0, stream>>>((const float*)d_ws, rois, out);
  } else {
    int total = K * CC * PHW;
    k_roialign_direct<<<(total + 255) / 256, 256, 0, stream>>>(features, rois, out, total);
  }
}

// Round 2
// 96.619 us; speedup vs baseline: 1.5674x; 1.5674x over previous
//
#include <hip/hip_runtime.h>
#include <hip/hip_fp16.h>

#define CC 256
#define HH 200
#define WW 304
#define PHW 49   // 7*7

struct Interp { int lo, hi; float w0, w1; };

__device__ __forceinline__ Interp axis_interp(float coord, int size) {
  float valid = (coord >= -1.0f && coord <= (float)size) ? 1.0f : 0.0f;
  float c = fminf(fmaxf(coord, 0.0f), (float)(size - 1));
  float fl = floorf(c);
  int lo = (int)fl;
  int hi = min(lo + 1, size - 1);
  float fr = c - fl;
  Interp r;
  r.lo = lo; r.hi = hi;
  r.w0 = (1.0f - fr) * valid;
  r.w1 = fr * valid;
  return r;
}

__device__ __forceinline__ float4 h4_to_f4(ushort4 u) {
  __half2 a = *(__half2*)&u.x;
  __half2 b = *(__half2*)&u.z;
  float2 fa = __half22float2(a);
  float2 fb = __half22float2(b);
  return make_float4(fa.x, fa.y, fb.x, fb.y);
}

// NCHW fp32 -> NHWC fp16: dst[((b*H+y)*W+x)*C + c] = (half)src[((b*C+c)*H+y)*W + x]
// Tile: 128 channels x 32 x. 256 threads.
__global__ __launch_bounds__(256) void k_transpose_f16(const float* __restrict__ src,
                                                       __half* __restrict__ dst) {
  __shared__ float tile[128][33];
  int plane = blockIdx.z;              // b*HH + y
  int x0 = blockIdx.x * 32;
  int c0 = blockIdx.y * 128;
  int b = plane / HH;
  int y = plane - b * HH;
  const float* sp = src + ((size_t)b * CC + c0) * HH * WW + (size_t)y * WW + x0;
  int tx = threadIdx.x & 31;
  int tc = threadIdx.x >> 5;           // 0..7
  bool xok = (x0 + tx) < WW;
#pragma unroll
  for (int q = 0; q < 16; ++q) {
    int c = tc + q * 8;
    tile[c][tx] = xok ? sp[(size_t)c * HH * WW + tx] : 0.0f;
  }
  __syncthreads();
  __half* dp = dst + ((size_t)plane * WW + x0) * CC + c0;
  int q = threadIdx.x & 31;            // channel quad (4 ch each)
  int xr0 = threadIdx.x >> 5;          // 0..7
#pragma unroll
  for (int it = 0; it < 4; ++it) {
    int xr = xr0 + it * 8;
    if ((x0 + xr) < WW) {
      float f0 = tile[q * 4 + 0][xr];
      float f1 = tile[q * 4 + 1][xr];
      float f2 = tile[q * 4 + 2][xr];
      float f3 = tile[q * 4 + 3][xr];
      union { ushort4 u; __half2 h[2]; } pk;
      pk.h[0] = __floats2half2_rn(f0, f1);
      pk.h[1] = __floats2half2_rn(f2, f3);
      *(ushort4*)(dp + (size_t)xr * CC + q * 4) = pk.u;
    }
  }
}

// One block (512 thr = 8 waves) per ROI. Wave handles bins p = wave, wave+8, ...
// Lane holds channels [4*lane, 4*lane+4). NHWC fp16 gathers: ushort4, coalesced.
__global__ __launch_bounds__(512) void k_roialign_nhwc_f16(const __half* __restrict__ fe,
                                                           const float* __restrict__ rois,
                                                           float* __restrict__ out) {
  __shared__ float lds[PHW * 257];     // [p][c] padded
  int k = blockIdx.x;
  const float* r = rois + (size_t)k * 5;
  int b = (int)r[0];
  float x1 = r[1] * 0.25f, y1 = r[2] * 0.25f;
  float x2 = r[3] * 0.25f, y2 = r[4] * 0.25f;
  float bin_w = fmaxf(x2 - x1, 1.0f) * (1.0f / 7.0f);
  float bin_h = fmaxf(y2 - y1, 1.0f) * (1.0f / 7.0f);

  int wave = threadIdx.x >> 6;         // 0..7
  int lane = threadIdx.x & 63;
  const __half* base = fe + (size_t)b * HH * WW * CC + (size_t)lane * 4;

  for (int p = wave; p < PHW; p += 8) {
    int ph = p / 7;
    int pw = p - ph * 7;
    float4 acc = make_float4(0.f, 0.f, 0.f, 0.f);
#pragma unroll
    for (int sy = 0; sy < 2; ++sy) {
      float yy = y1 + ((float)(2 * ph + sy) + 0.5f) * 0.5f * bin_h;
      Interp iy = axis_interp(yy, HH);
#pragma unroll
      for (int sx = 0; sx < 2; ++sx) {
        float xx = x1 + ((float)(2 * pw + sx) + 0.5f) * 0.5f * bin_w;
        Interp ix = axis_interp(xx, WW);
        const ushort4 u00 = *(const ushort4*)(base + ((size_t)iy.lo * WW + ix.lo) * CC);
        const ushort4 u01 = *(const ushort4*)(base + ((size_t)iy.lo * WW + ix.hi) * CC);
        const ushort4 u10 = *(const ushort4*)(base + ((size_t)iy.hi * WW + ix.lo) * CC);
        const ushort4 u11 = *(const ushort4*)(base + ((size_t)iy.hi * WW + ix.hi) * CC);
        float4 v00 = h4_to_f4(u00), v01 = h4_to_f4(u01);
        float4 v10 = h4_to_f4(u10), v11 = h4_to_f4(u11);
        float w00 = iy.w0 * ix.w0, w01 = iy.w0 * ix.w1;
        float w10 = iy.w1 * ix.w0, w11 = iy.w1 * ix.w1;
        acc.x += w00 * v00.x + w01 * v01.x + w10 * v10.x + w11 * v11.x;
        acc.y += w00 * v00.y + w01 * v01.y + w10 * v10.y + w11 * v11.y;
        acc.z += w00 * v00.z + w01 * v01.z + w10 * v10.z + w11 * v11.z;
        acc.w += w00 * v00.w + w01 * v01.w + w10 * v10.w + w11 * v11.w;
      }
    }
    int o = p * 257 + lane * 4;
    lds[o + 0] = acc.x * 0.25f;
    lds[o + 1] = acc.y * 0.25f;
    lds[o + 2] = acc.z * 0.25f;
    lds[o + 3] = acc.w * 0.25f;
  }
  __syncthreads();

  float* outk = out + (size_t)k * CC * PHW;
  for (int i = threadIdx.x; i < CC * PHW; i += 512) {
    int c = i / PHW;
    int p = i - c * PHW;
    outk[i] = lds[p * 257 + c];
  }
}

// Fallback if workspace too small: one thread per output element, NCHW fp32.
__global__ __launch_bounds__(256) void k_roialign_direct(const float* __restrict__ fe,
                                                         const float* __restrict__ rois,
                                                         float* __restrict__ out,
                                                         int total) {
  int idx = blockIdx.x * 256 + threadIdx.x;
  if (idx >= total) return;
  int pw = idx % 7;
  int t = idx / 7;
  int ph = t % 7; t /= 7;
  int c = t % CC;
  int k = t / CC;
  const float* r = rois + (size_t)k * 5;
  int b = (int)r[0];
  float x1 = r[1] * 0.25f, y1 = r[2] * 0.25f;
  float x2 = r[3] * 0.25f, y2 = r[4] * 0.25f;
  float bin_w = fmaxf(x2 - x1, 1.0f) * (1.0f / 7.0f);
  float bin_h = fmaxf(y2 - y1, 1.0f) * (1.0f / 7.0f);
  const float* base = fe + ((size_t)b * CC + c) * HH * WW;
  float acc = 0.f;
#pragma unroll
  for (int sy = 0; sy < 2; ++sy) {
    float yy = y1 + ((float)(2 * ph + sy) + 0.5f) * 0.5f * bin_h;
    Interp iy = axis_interp(yy, HH);
#pragma unroll
    for (int sx = 0; sx < 2; ++sx) {
      float xx = x1 + ((float)(2 * pw + sx) + 0.5f) * 0.5f * bin_w;
      Interp ix = axis_interp(xx, WW);
      float v00 = base[(size_t)iy.lo * WW + ix.lo];
      float v01 = base[(size_t)iy.lo * WW + ix.hi];
      float v10 = base[(size_t)iy.hi * WW + ix.lo];
      float v11 = base[(size_t)iy.hi * WW + ix.hi];
      acc += iy.w0 * ix.w0 * v00 + iy.w0 * ix.w1 * v01 +
             iy.w1 * ix.w0 * v10 + iy.w1 * ix.w1 * v11;
    }
  }
  out[idx] = acc * 0.25f;
}

extern "C" void kernel_launch(void* const* d_in, const int* in_sizes, int n_in,
                              void* d_out, int out_size, void* d_ws, size_t ws_size,
                              hipStream_t stream) {
  const float* features = (const float*)d_in[0];
  const float* rois = (const float*)d_in[1];
  float* out = (float*)d_out;
  int B = in_sizes[0] / (CC * HH * WW);
  int K = in_sizes[1] / 5;
  size_t need = (size_t)B * HH * WW * CC * sizeof(__half);
  if (ws_size >= need) {
    dim3 tg((WW + 31) / 32, CC / 128, B * HH);
    k_transpose_f16<<<tg, 256, 0, stream>>>(features, (__half*)d_ws);
    k_roialign_nhwc_f16<<<K, 512, 0, stream>>>((const __half*)d_ws, rois, out);
  } else {
    int total = K * CC * PHW;
    k_roialign_direct<<<(total + 255) / 256, 256, 0, stream>>>(features, rois, out, total);
  }
}